// Round 12
// baseline (369.473 us; speedup 1.0000x reference)
//
#include <hip/hip_runtime.h>

typedef __attribute__((ext_vector_type(4))) float f32x4;
typedef __attribute__((ext_vector_type(8))) short s16x8;
typedef unsigned short u16;
typedef unsigned int   u32;

#define NBATCH 8
#define ICN 256
#define OCN 128
#define VOLP 36432     // padded per-(n,oc) y volume (all classes, 16-float aligned)
#define WRE 884736     // 27*8*8*512 = 27*256*128
#define XTE 8388608    // 8*256*4096
#define ZBF 4096       // zero-buffer floats (16 KB)
#define S1POOL 78336   // 2 A-buffers x (18 rows x 17 x 32ic x 2B x hi/lo) = 2*39168

// padded class offsets / plane strides (16-float aligned)
__host__ __device__ constexpr int cls_yoff2(int c){
  return (c==0)?0:(c==1)?5168:(c==2)?9792:(c==3)?14416:
         (c==4)?18768:(c==5)?23632:(c==6)?27984:32336;
}
__host__ __device__ constexpr int cls_nxyp(int c){
  return ((c&3)==0)?304:((c&3)==3)?256:272;
}

__device__ __forceinline__ u16 f2bf(float v){
  u32 u = __float_as_uint(v);
  u32 r = u + 0x7FFFu + ((u>>16)&1u);
  return (u16)(r>>16);
}
__device__ __forceinline__ float bf2f(u16 b){ return __uint_as_float(((u32)b)<<16); }

#define GLOAD16(gp, lp)                                                        \
  __builtin_amdgcn_global_load_lds(                                            \
      (const __attribute__((address_space(1))) void*)(gp),                     \
      (__attribute__((address_space(3))) void*)(lp), 16, 0, 0)

// ---- prep_w2: w[oc][ic][27] fp32 -> w2[tap27][icc8][og8][lane64][e8] bf16 hi/lo ----
// also zeroes the 16 KB zero-buffer (blocks 0..15)
__global__ __launch_bounds__(256) void prep_w2(const float* __restrict__ w,
                                               u16* __restrict__ wh, u16* __restrict__ wl,
                                               float* __restrict__ zb){
  if (blockIdx.x < 16) zb[blockIdx.x*256 + threadIdx.x] = 0.f;
  int idx = blockIdx.x*256 + threadIdx.x;   // WRE exactly
  int e = idx&7, ln=(idx>>3)&63, og=(idx>>9)&7, icc=(idx>>12)&7, tt=idx>>15;
  int oc = og*16 + (ln&15);
  int ic = icc*32 + ((ln>>4)&3)*8 + e;
  const int toffs[8] = {0,8,12,16,18,22,24,26};
  const int tcnt[8]  = {8,4,4,2,4,2,2,1};
  int c=0, t=0;
  #pragma unroll
  for (int cc=0; cc<8; ++cc)
    if (tt>=toffs[cc] && tt<toffs[cc]+tcnt[cc]){ c=cc; t=tt-toffs[cc]; }
  int ez=c>>2, ey=(c>>1)&1, ex=c&1;
  int ty=2-ey, tx=2-ex;
  int ax=t%tx, ay=(t/tx)%ty, az=t/(tx*ty);
  int qz = ez?1:(az?2:0), qy = ey?1:(ay?2:0), qx = ex?1:(ax?2:0);
  float v = w[((size_t)oc*ICN + ic)*27 + (qz*3+qy)*3+qx];
  u16 h = f2bf(v);
  wh[idx] = h;
  wl[idx] = f2bf(v - bf2f(h));
}

// ---- prep_x: x[n][ic][4096] fp32 -> x2[n][icc8][4096 pos][32 ic] bf16 hi/lo ----
__global__ __launch_bounds__(256) void prep_x(const float* __restrict__ x,
                                              u16* __restrict__ xh, u16* __restrict__ xl){
  u32 o = blockIdx.x*256 + threadIdx.x;   // XTE exactly
  int il = o & 31, p = (o>>5)&4095, icc = (o>>17)&7, n = o>>20;
  float v = x[(size_t)(n*256 + icc*32 + il)*4096 + p];
  u16 h = f2bf(v);
  xh[o] = h;
  xl[o] = f2bf(v - bf2f(h));
}

// ---- async A staging: NCH chunks of 16 B per half, linear LDS dest ----
#define S1_ISSUE(BUFBYTE, ICCV, AZV)                                           \
  {                                                                            \
    _Pragma("unroll")                                                          \
    for (int k_=0; k_<KITER; ++k_){                                            \
      const int s0_ = k_*256 + wv*64;                                          \
      if (s0_ < NCH){                                                          \
        const int s_ = s0_ + ln;                                               \
        const int icg_ = s_&3, pos_ = s_>>2;                                   \
        const int xi_ = pos_%17, yi_ = pos_/17;                                \
        const int zc_ = EZ ? mz : (mz-1+(AZV));                                \
        const int yc_ = my0 + yi_ + (EY-1);                                    \
        const int xc_ = xi_ + (EX-1);                                          \
        const bool inb_ = (u32)zc_<16u && (u32)yc_<16u && (u32)xc_<16u;        \
        const size_t g_ = nbase + (size_t)(ICCV)*131072                        \
                        + (size_t)((zc_*256+yc_*16+xc_)*32 + icg_*8);          \
        const u16* gh_ = inb_ ? (xh+g_) : zb16;                                \
        const u16* gl_ = inb_ ? (xl+g_) : zb16;                                \
        char* lh_ = pool + (BUFBYTE) + s0_*16;                                 \
        char* ll_ = pool + (BUFBYTE) + APOSP*64 + s0_*16;                      \
        if (s_ < NCH){                                                         \
          GLOAD16(gh_, lh_);                                                   \
          GLOAD16(gl_, ll_);                                                   \
        }                                                                      \
      }                                                                        \
    }                                                                          \
  }

// ---- stage 1 body: per-class dense conv via split-bf16 MFMA; B-frags from L2 ----
// block 256 (4 waves): wave = (mhalf)*128m x (ochalf)*64oc, acc[FI][4]
// FI = m-fragments per wave (8 main; 1/3 tails, tails duplicate across mhalf)
template<int EZ,int EY,int EX,int FI>
__device__ __forceinline__ void s1body(char* pool,
                                       const u16* __restrict__ xh, const u16* __restrict__ xl,
                                       const u16* __restrict__ wh, const u16* __restrict__ wl,
                                       const u16* __restrict__ zb16,
                                       float* __restrict__ yd, int n0, int mt, int mz, int nl, int tid)
{
  constexpr int TZ=2-EZ, TY=2-EY, TX=2-EX;
  constexpr int DX=17-EX;
  constexpr int DY=17-EY;
  constexpr int NXY=DY*DX;
  constexpr int CLS = EZ*4+EY*2+EX;
  constexpr int YOFF = cls_yoff2(CLS);
  constexpr int NXYP = cls_nxyp(CLS);
  constexpr int W27 = (CLS==0)?0:(CLS==1)?8:(CLS==2)?12:(CLS==3)?16:
                      (CLS==4)?18:(CLS==5)?22:(CLS==6)?24:26;
  constexpr int ROWS  = (FI==8)?18:4;
  constexpr int APOSP = ROWS*17;
  constexpr int NCH   = APOSP*4;        // 16B chunks per half
  constexpr int KITER = (NCH+255)/256;
  constexpr int BUFB  = APOSP*128;      // bytes per buffer (hi+lo)
  constexpr int NST   = TZ*8;
  u16* AsU = (u16*)pool;

  const int wv=tid>>6, ln=tid&63;
  const int mhalf = wv&1, ochalf = wv>>1;
  const int my0 = (mt*256)/DX;
  const int mbase = mt*256 + ((FI==8)? mhalf*128 : 0);

  int posA[FI];
  #pragma unroll
  for (int fi=0; fi<FI; ++fi){
    int m = mbase + fi*16 + (ln&15);
    if (m > NXY-1) m = NXY-1;      // clamp (stores guarded)
    int my=m/DX, mx=m-my*DX;
    posA[fi] = ((my-my0)*17 + mx)*32 + (ln>>4)*8;
  }

  f32x4 acc[FI][4];
  #pragma unroll
  for (int i=0;i<FI;++i)
    #pragma unroll
    for (int j=0;j<4;++j) acc[i][j]=(f32x4){0.f,0.f,0.f,0.f};

  const size_t nbase = (size_t)(n0+nl)*(ICN*4096);

  S1_ISSUE(0, 0, 0);
  __syncthreads();

  int st = 0;
  #pragma unroll 1
  for (int icc=0; icc<8; ++icc){
    #pragma unroll
    for (int az=0; az<TZ; ++az){
      const int cur = st & 1;
      const bool have_next = (st+1) < NST;
      if (have_next){
        const int nicc = (az+1<TZ)?icc:(icc+1);
        const int naz  = (az+1<TZ)?(az+1):0;
        S1_ISSUE((cur^1)*BUFB, nicc, naz);
      }
      const int curo = cur*(BUFB/2);   // u16 offset of current buffer

      #pragma unroll
      for (int ay=0; ay<TY; ++ay)
      #pragma unroll
      for (int ax=0; ax<TX; ++ax){
        const int t = (az*TY+ay)*TX+ax;
        const int toff = (ay*17+ax)*32;
        const u16* bp = wh + (size_t)(((W27+t)*8+icc)*8)*512 + (ochalf*4)*512 + ln*8;
        const u16* bq = wl + (size_t)(((W27+t)*8+icc)*8)*512 + (ochalf*4)*512 + ln*8;
        s16x8 bh[4], bl[4];
        #pragma unroll
        for (int og=0; og<4; ++og) bh[og] = *(const s16x8*)(bp + og*512);
        #pragma unroll
        for (int og=0; og<4; ++og) bl[og] = *(const s16x8*)(bq + og*512);
        #pragma unroll
        for (int fi=0; fi<FI; ++fi){
          s16x8 ah = *(const s16x8*)&AsU[curo + posA[fi]+toff];
          s16x8 al = *(const s16x8*)&AsU[curo + APOSP*32 + posA[fi]+toff];
          #pragma unroll
          for (int og=0; og<4; ++og){
            acc[fi][og] = __builtin_amdgcn_mfma_f32_16x16x32_bf16(ah, bh[og], acc[fi][og],0,0,0);
            acc[fi][og] = __builtin_amdgcn_mfma_f32_16x16x32_bf16(al, bh[og], acc[fi][og],0,0,0);
            acc[fi][og] = __builtin_amdgcn_mfma_f32_16x16x32_bf16(ah, bl[og], acc[fi][og],0,0,0);
          }
        }
      }
      __syncthreads();   // drains gload_lds queue (next buffer ready) + read fence
      ++st;
    }
  }

  // epilogue: per-wave transpose (NPASS half-passes of 32 m), aligned dense nt store
  float* tr = (float*)pool + wv*(64*33);
  constexpr int NPASS = (FI+1)/2;
  #pragma unroll
  for (int pass=0; pass<NPASS; ++pass){
    #pragma unroll
    for (int fi2=0; fi2<2; ++fi2){
      if (pass*2+fi2 < FI){
        #pragma unroll
        for (int og=0; og<4; ++og)
          #pragma unroll
          for (int j=0; j<4; ++j)
            tr[(og*16+(ln&15))*33 + fi2*16 + (ln>>4)*4 + j] = acc[pass*2+fi2][og][j];
      }
    }
    const int mcol = pass*32 + (ln&31);
    const int m = mbase + mcol;
    const bool valid = (m < NXY) && (mcol < FI*16) && (FI==8 || mhalf==0);
    size_t lbase = (size_t)YOFF + (size_t)mz*NXYP + (valid ? m : 0);
    #pragma unroll 4
    for (int i=0; i<32; ++i){
      int r = 2*i + (ln>>5);
      float v = tr[r*33 + (ln&31)];
      int oc = ochalf*64 + r;
      if (valid)
        __builtin_nontemporal_store(v, yd + (size_t)(nl*128 + oc)*VOLP + lbase);
    }
  }
}

// ---- fused stage 1: 231 tiles/n = per mz-group 7 subs (4 mains + 3 tails) ----
__global__ __launch_bounds__(256,2) void stage1f(const u16* __restrict__ xh, const u16* __restrict__ xl,
                                                 const u16* __restrict__ wh, const u16* __restrict__ wl,
                                                 const u16* __restrict__ zb16,
                                                 float* __restrict__ yd, int n0){
  __shared__ __align__(16) char pool[S1POOL];
  int bid = blockIdx.x, nl, tid = threadIdx.x;
  if (gridDim.z == 1){ nl = bid & 7; bid >>= 3; }
  else               { nl = blockIdx.z; }
  int mz, sub, ez;
  if (bid < 119){ ez = 0; mz = bid/7;  sub = bid - mz*7; }
  else          { int b2 = bid-119; ez = 1; mz = b2/7; sub = b2 - mz*7; }
  if (ez == 0){
    switch(sub){
      case 0: s1body<0,0,0,8>(pool,xh,xl,wh,wl,zb16,yd,n0,0,mz,nl,tid); break;
      case 1: s1body<0,0,0,3>(pool,xh,xl,wh,wl,zb16,yd,n0,1,mz,nl,tid); break;
      case 2: s1body<0,0,1,8>(pool,xh,xl,wh,wl,zb16,yd,n0,0,mz,nl,tid); break;
      case 3: s1body<0,0,1,1>(pool,xh,xl,wh,wl,zb16,yd,n0,1,mz,nl,tid); break;
      case 4: s1body<0,1,0,8>(pool,xh,xl,wh,wl,zb16,yd,n0,0,mz,nl,tid); break;
      case 5: s1body<0,1,0,1>(pool,xh,xl,wh,wl,zb16,yd,n0,1,mz,nl,tid); break;
      default:s1body<0,1,1,8>(pool,xh,xl,wh,wl,zb16,yd,n0,0,mz,nl,tid); break;
    }
  } else {
    switch(sub){
      case 0: s1body<1,0,0,8>(pool,xh,xl,wh,wl,zb16,yd,n0,0,mz,nl,tid); break;
      case 1: s1body<1,0,0,3>(pool,xh,xl,wh,wl,zb16,yd,n0,1,mz,nl,tid); break;
      case 2: s1body<1,0,1,8>(pool,xh,xl,wh,wl,zb16,yd,n0,0,mz,nl,tid); break;
      case 3: s1body<1,0,1,1>(pool,xh,xl,wh,wl,zb16,yd,n0,1,mz,nl,tid); break;
      case 4: s1body<1,1,0,8>(pool,xh,xl,wh,wl,zb16,yd,n0,0,mz,nl,tid); break;
      case 5: s1body<1,1,0,1>(pool,xh,xl,wh,wl,zb16,yd,n0,1,mz,nl,tid); break;
      default:s1body<1,1,1,8>(pool,xh,xl,wh,wl,zb16,yd,n0,0,mz,nl,tid); break;
    }
  }
}

// ---- stage 2: gather parity subplanes (padded class-dense y) + separable FIR + bias ----
__global__ __launch_bounds__(256) void stage2d(const float* __restrict__ yd, const float* __restrict__ bias,
                                               float* __restrict__ out, int n0){
  __shared__ float raw[33][36];
  __shared__ float fx[35][36];
  const int tid=threadIdx.x;
  const int zg=blockIdx.x, oc=blockIdx.y, nl=blockIdx.z;
  const float* yb = yd + (size_t)(nl*128+oc)*VOLP;
  const float b = bias[oc];
  float* ob = out + (size_t)((n0+nl)*128+oc)*32768;
  for (int t2=tid; t2<1188; t2+=256) raw[t2/36][t2%36] = 0.f;
  if (tid < 72){ fx[(tid>=36)?34:0][tid%36] = 0.f; }
  __syncthreads();
  float a0[4]={0,0,0,0}, a1[4]={0,0,0,0}, a2[4]={0,0,0,0};
  #pragma unroll 1
  for (int s=0; s<19; ++s){
    int uz = zg*16 - 1 + s;
    if ((u32)uz < 33u){
      const int cz = uz & 1, zi = uz >> 1;
      #pragma unroll
      for (int cy=0; cy<2; ++cy)
        #pragma unroll
        for (int cx=0; cx<2; ++cx){
          const int DXc = 17-cx;
          const int NXYc = (17-cy)*DXc;
          const int NXYPc = cls_nxyp(cy*2+cx);
          const int yoff = (cz ? cls_yoff2(4+cy*2+cx) : cls_yoff2(cy*2+cx)) + zi*NXYPc;
          const float* sp = yb + yoff;
          for (int s2=tid; s2<NXYc; s2+=256){
            int r = s2/DXc, c2 = s2 - r*DXc;
            raw[2*r+cy][2*c2+cx+1] = __builtin_nontemporal_load(sp + s2);
          }
        }
    } else {
      for (int t2=tid; t2<1188; t2+=256) raw[t2/36][t2%36] = 0.f;
    }
    __syncthreads();
    for (int t2=tid; t2<1056; t2+=256){
      int uy = t2>>5, ox = t2&31;
      fx[uy+1][ox] = 0.25f*raw[uy][ox] + 0.75f*raw[uy][ox+1]
                   + 0.75f*raw[uy][ox+2] + 0.25f*raw[uy][ox+3];
    }
    __syncthreads();
    #pragma unroll
    for (int k=0;k<4;++k){
      int pos = tid + k*256;
      int oy = pos>>5, ox = pos&31;
      float fv = 0.25f*fx[oy][ox] + 0.75f*fx[oy+1][ox]
               + 0.75f*fx[oy+2][ox] + 0.25f*fx[oy+3][ox];
      if (s >= 3){
        int oz = zg*16 + s - 3;
        __builtin_nontemporal_store(a0[k] + 0.25f*fv + b, ob + (size_t)oz*1024 + pos);
      }
      a0[k] = a1[k] + 0.75f*fv;
      a1[k] = a2[k] + 0.75f*fv;
      a2[k] = 0.25f*fv;
    }
    __syncthreads();
  }
}

extern "C" void kernel_launch(void* const* d_in, const int* in_sizes, int n_in,
                              void* d_out, int out_size, void* d_ws, size_t ws_size,
                              hipStream_t stream) {
  const float* x    = (const float*)d_in[0];
  const float* w    = (const float*)d_in[1];
  const float* bias = (const float*)d_in[2];
  float* out = (float*)d_out;

  float* zb = (float*)d_ws;
  u16* wh = (u16*)(zb + ZBF);
  u16* wl = wh + WRE;
  u16* xh = wl + WRE;
  u16* xl = xh + XTE;
  float* yd = (float*)(xl + XTE);
  size_t base = (size_t)ZBF*4 + (size_t)(2*WRE + 2*XTE)*2;

  int nChunk = 1;
  if      (ws_size >= base + (size_t)8*128*VOLP*4) nChunk=8;
  else if (ws_size >= base + (size_t)4*128*VOLP*4) nChunk=4;
  else if (ws_size >= base + (size_t)2*128*VOLP*4) nChunk=2;

  prep_w2<<<dim3(WRE/256), 256, 0, stream>>>(w, wh, wl, zb);
  prep_x<<<dim3(XTE/256), 256, 0, stream>>>(x, xh, xl);

  const u16* zb16 = (const u16*)zb;
  if (nChunk == 8){
    stage1f<<<dim3(1848,1,1),256,0,stream>>>(xh,xl,wh,wl,zb16,yd,0);
    stage2d<<<dim3(2,128,8),256,0,stream>>>(yd,bias,out,0);
  } else {
    for (int n0=0; n0<NBATCH; n0+=nChunk){
      stage1f<<<dim3(231,1,nChunk),256,0,stream>>>(xh,xl,wh,wl,zb16,yd,n0);
      stage2d<<<dim3(2,128,nChunk),256,0,stream>>>(yd,bias,out,n0);
    }
  }
}

// Round 13
// 352.940 us; speedup vs baseline: 1.0468x; 1.0468x over previous
//
#include <hip/hip_runtime.h>

typedef __attribute__((ext_vector_type(4))) float f32x4;
typedef __attribute__((ext_vector_type(8))) short s16x8;
typedef unsigned short u16;
typedef unsigned int   u32;

#define NBATCH 8
#define ICN 256
#define OCN 128
#define VOLP 36432     // padded per-(n,oc) y volume (all classes, 16-float aligned)
#define WRE 884736     // 27*8*8*512 = 27*256*128
#define XTE 8388608    // 8*256*4096
#define ZBF 4096       // zero-buffer floats (16 KB)
// staging: 2 plane buffers x (hi+lo) x 170 pos x 32 ic x 2B = 2*21760 B
#define S1POOL 43520   // > epilogue transpose 33792

// padded class offsets / plane strides (16-float aligned)
__host__ __device__ constexpr int cls_yoff2(int c){
  return (c==0)?0:(c==1)?5168:(c==2)?9792:(c==3)?14416:
         (c==4)?18768:(c==5)?23632:(c==6)?27984:32336;
}
__host__ __device__ constexpr int cls_nxyp(int c){
  return ((c&3)==0)?304:((c&3)==3)?256:272;
}

__device__ __forceinline__ u16 f2bf(float v){
  u32 u = __float_as_uint(v);
  u32 r = u + 0x7FFFu + ((u>>16)&1u);
  return (u16)(r>>16);
}
__device__ __forceinline__ float bf2f(u16 b){ return __uint_as_float(((u32)b)<<16); }

#define GLOAD16(gp, lp)                                                        \
  __builtin_amdgcn_global_load_lds(                                            \
      (const __attribute__((address_space(1))) void*)(gp),                     \
      (__attribute__((address_space(3))) void*)(lp), 16, 0, 0)

// ---- prep_w2: w[oc][ic][27] fp32 -> w2[tap27][icc8][og8][lane64][e8] bf16 hi/lo ----
// also zeroes the 16 KB zero-buffer (blocks 0..15)
__global__ __launch_bounds__(256) void prep_w2(const float* __restrict__ w,
                                               u16* __restrict__ wh, u16* __restrict__ wl,
                                               float* __restrict__ zb){
  if (blockIdx.x < 16) zb[blockIdx.x*256 + threadIdx.x] = 0.f;
  int idx = blockIdx.x*256 + threadIdx.x;   // WRE exactly
  int e = idx&7, ln=(idx>>3)&63, og=(idx>>9)&7, icc=(idx>>12)&7, tt=idx>>15;
  int oc = og*16 + (ln&15);
  int ic = icc*32 + ((ln>>4)&3)*8 + e;
  const int toffs[8] = {0,8,12,16,18,22,24,26};
  const int tcnt[8]  = {8,4,4,2,4,2,2,1};
  int c=0, t=0;
  #pragma unroll
  for (int cc=0; cc<8; ++cc)
    if (tt>=toffs[cc] && tt<toffs[cc]+tcnt[cc]){ c=cc; t=tt-toffs[cc]; }
  int ez=c>>2, ey=(c>>1)&1, ex=c&1;
  int ty=2-ey, tx=2-ex;
  int ax=t%tx, ay=(t/tx)%ty, az=t/(tx*ty);
  int qz = ez?1:(az?2:0), qy = ey?1:(ay?2:0), qx = ex?1:(ax?2:0);
  float v = w[((size_t)oc*ICN + ic)*27 + (qz*3+qy)*3+qx];
  u16 h = f2bf(v);
  wh[idx] = h;
  wl[idx] = f2bf(v - bf2f(h));
}

// ---- prep_x: x[n][ic][4096] fp32 -> x2[n][icc8][4096 pos][32 ic] bf16 hi/lo ----
__global__ __launch_bounds__(256) void prep_x(const float* __restrict__ x,
                                              u16* __restrict__ xh, u16* __restrict__ xl){
  u32 o = blockIdx.x*256 + threadIdx.x;   // XTE exactly
  int il = o & 31, p = (o>>5)&4095, icc = (o>>17)&7, n = o>>20;
  float v = x[(size_t)(n*256 + icc*32 + il)*4096 + p];
  u16 h = f2bf(v);
  xh[o] = h;
  xl[o] = f2bf(v - bf2f(h));
}

// ---- async A-plane staging: 680 chunks of 16 B per half ----
// wave wv handles chunks [wv*170, (wv+1)*170) -> exactly 6 gload_lds per wave
// chunk s: pos = s>>2 (10 rows x 17 x), icg = s&3; lds byte = s*16
#define S1_ISSUE(BUFBYTE, ICCV, AZV)                                           \
  {                                                                            \
    _Pragma("unroll")                                                          \
    for (int j_=0; j_<3; ++j_){                                                \
      const int r_ = j_*64 + ln;                                               \
      if (r_ < 170){                                                           \
        const int s_ = wv*170 + r_;                                            \
        const int icg_ = s_&3, pos_ = s_>>2;                                   \
        const int xi_ = pos_%17, yi_ = pos_/17;                                \
        const int zc_ = EZ ? mz : (mz-1+(AZV));                                \
        const int yc_ = my0 + yi_ + (EY-1);                                    \
        const int xc_ = xi_ + (EX-1);                                          \
        const bool inb_ = (u32)zc_<16u && (u32)yc_<16u && (u32)xc_<16u;        \
        const size_t g_ = nbase + (size_t)(ICCV)*131072                        \
                        + (size_t)((zc_*256+yc_*16+xc_)*32 + icg_*8);          \
        const u16* gh_ = inb_ ? (xh+g_) : zb16;                                \
        const u16* gl_ = inb_ ? (xl+g_) : zb16;                                \
        char* lh_ = pool + (BUFBYTE) + s_*16;                                  \
        char* ll_ = pool + (BUFBYTE) + 10880 + s_*16;                          \
        GLOAD16(gh_, lh_);                                                     \
        GLOAD16(gl_, ll_);                                                     \
      }                                                                        \
    }                                                                          \
  }

// ---- stage 1 body: per-class dense conv via split-bf16 MFMA; B-frags from L2 ----
// block 256 (4 waves): wave = (mhalf = wv&1)*64m x (ochalf = wv>>1)*64oc
// A staged via double-buffered global_load_lds, counted-vmcnt pipeline (T4)
template<int EZ,int EY,int EX>
__device__ __forceinline__ void s1body(char* pool,
                                       const u16* __restrict__ xh, const u16* __restrict__ xl,
                                       const u16* __restrict__ wh, const u16* __restrict__ wl,
                                       const u16* __restrict__ zb16,
                                       float* __restrict__ yd, int n0, int mt, int mz, int nl, int tid)
{
  constexpr int TZ=2-EZ, TY=2-EY, TX=2-EX;
  constexpr int DX=17-EX;
  constexpr int DY=17-EY;
  constexpr int NXY=DY*DX;
  constexpr int CLS = EZ*4+EY*2+EX;
  constexpr int YOFF = cls_yoff2(CLS);
  constexpr int NXYP = cls_nxyp(CLS);
  constexpr int W27 = (CLS==0)?0:(CLS==1)?8:(CLS==2)?12:(CLS==3)?16:
                      (CLS==4)?18:(CLS==5)?22:(CLS==6)?24:26;
  constexpr int NST = TZ*8;        // total plane-stages
  u16* AsU = (u16*)pool;           // per buffer: 10880 u16 (hi 5440, lo 5440)

  const int wv=tid>>6, ln=tid&63;
  const int mhalf = wv&1, ochalf = wv>>1;
  const int my0=(mt*128)/DX;

  int posA[4];
  #pragma unroll
  for (int fi=0; fi<4; ++fi){
    int m = mt*128 + mhalf*64 + fi*16 + (ln&15);
    if (m > NXY-1) m = NXY-1;      // clamp (stores guarded)
    int my=m/DX, mx=m-my*DX;
    posA[fi] = ((my-my0)*17 + mx)*32 + (ln>>4)*8;
  }

  f32x4 acc[4][4];
  #pragma unroll
  for (int i=0;i<4;++i)
    #pragma unroll
    for (int j=0;j<4;++j) acc[i][j]=(f32x4){0.f,0.f,0.f,0.f};

  const size_t nbase = (size_t)(n0+nl)*(ICN*4096);

  S1_ISSUE(0, 0, 0);

  int st = 0;
  #pragma unroll 1
  for (int icc=0; icc<8; ++icc){
    #pragma unroll
    for (int az=0; az<TZ; ++az){
      const int cur = st & 1;
      const bool have_next = (st+1) < NST;
      if (have_next){
        const int nicc = (az+1<TZ)?icc:(icc+1);
        const int naz  = (az+1<TZ)?(az+1):0;
        S1_ISSUE((cur^1)*21760, nicc, naz);
        // wait only for the PREVIOUS stage's 6 DMAs (in-order vmcnt), keep 6 in flight
        asm volatile("s_waitcnt vmcnt(6)" ::: "memory");
      } else {
        asm volatile("s_waitcnt vmcnt(0)" ::: "memory");
      }
      asm volatile("s_barrier" ::: "memory");   // current buffer fully written, all waves
      const int curo = cur*10880;

      #pragma unroll
      for (int ay=0; ay<TY; ++ay)
      #pragma unroll
      for (int ax=0; ax<TX; ++ax){
        const int t = (az*TY+ay)*TX+ax;
        const int toff = (ay*17+ax)*32;
        s16x8 ah[4], al[4];
        #pragma unroll
        for (int fi=0; fi<4; ++fi){
          ah[fi] = *(const s16x8*)&AsU[curo + posA[fi]+toff];
          al[fi] = *(const s16x8*)&AsU[curo + 5440 + posA[fi]+toff];
        }
        const u16* bp = wh + (size_t)(((W27+t)*8+icc)*8)*512 + (ochalf*4)*512 + ln*8;
        const u16* bq = wl + (size_t)(((W27+t)*8+icc)*8)*512 + (ochalf*4)*512 + ln*8;
        s16x8 bh[4], bl[4];
        #pragma unroll
        for (int og=0; og<4; ++og) bh[og] = *(const s16x8*)(bp + og*512);
        #pragma unroll
        for (int og=0; og<4; ++og) bl[og] = *(const s16x8*)(bq + og*512);
        #pragma unroll
        for (int fi=0; fi<4; ++fi)
          #pragma unroll
          for (int og=0; og<4; ++og){
            acc[fi][og] = __builtin_amdgcn_mfma_f32_16x16x32_bf16(ah[fi], bh[og], acc[fi][og],0,0,0);
            acc[fi][og] = __builtin_amdgcn_mfma_f32_16x16x32_bf16(al[fi], bh[og], acc[fi][og],0,0,0);
            acc[fi][og] = __builtin_amdgcn_mfma_f32_16x16x32_bf16(ah[fi], bl[og], acc[fi][og],0,0,0);
          }
      }
      // raw barrier (no vmcnt drain): all waves done READING cur before next
      // stage's DMA overwrites it; ds_reads were consumed by MFMA lgkm waits.
      asm volatile("s_barrier" ::: "memory");
      ++st;
    }
  }

  // epilogue: per-wave transpose (2 half-passes of 32 m), aligned dense nt store
  float* tr = (float*)pool + wv*(64*33);
  #pragma unroll
  for (int pass=0; pass<2; ++pass){
    #pragma unroll
    for (int fi=0; fi<2; ++fi)
      #pragma unroll
      for (int og=0; og<4; ++og)
        #pragma unroll
        for (int j=0; j<4; ++j)
          tr[(og*16+(ln&15))*33 + fi*16 + (ln>>4)*4 + j] = acc[pass*2+fi][og][j];
    int m = mt*128 + mhalf*64 + pass*32 + (ln&31);
    bool valid = m < NXY;
    size_t lbase = (size_t)YOFF + (size_t)mz*NXYP + (valid ? m : 0);
    #pragma unroll 4
    for (int i=0; i<32; ++i){
      int r = 2*i + (ln>>5);
      float v = tr[r*33 + (ln&31)];
      int oc = ochalf*64 + r;
      if (valid)
        __builtin_nontemporal_store(v, yd + (size_t)(nl*128 + oc)*VOLP + lbase);
    }
  }
}

// ---- fused stage 1 ----
__global__ __launch_bounds__(256,4) void stage1f(const u16* __restrict__ xh, const u16* __restrict__ xl,
                                                 const u16* __restrict__ wh, const u16* __restrict__ wl,
                                                 const u16* __restrict__ zb16,
                                                 float* __restrict__ yd, int n0){
  __shared__ __align__(16) char pool[S1POOL];
  int bid = blockIdx.x, nl, tid = threadIdx.x;
  if (gridDim.z == 1){ nl = bid & 7; bid >>= 3; }
  else               { nl = blockIdx.z; }
  int mz, sub;
  if (bid < 352){ mz = bid/22; sub = bid - mz*22; }
  else          { mz = 16;     sub = bid - 352;   }
  if      (sub <  3) s1body<0,0,0>(pool,xh,xl,wh,wl,zb16,yd,n0,sub   ,mz,nl,tid);
  else if (sub <  6) s1body<0,0,1>(pool,xh,xl,wh,wl,zb16,yd,n0,sub- 3,mz,nl,tid);
  else if (sub <  9) s1body<0,1,0>(pool,xh,xl,wh,wl,zb16,yd,n0,sub- 6,mz,nl,tid);
  else if (sub < 11) s1body<0,1,1>(pool,xh,xl,wh,wl,zb16,yd,n0,sub- 9,mz,nl,tid);
  else if (sub < 14) s1body<1,0,0>(pool,xh,xl,wh,wl,zb16,yd,n0,sub-11,mz,nl,tid);
  else if (sub < 17) s1body<1,0,1>(pool,xh,xl,wh,wl,zb16,yd,n0,sub-14,mz,nl,tid);
  else if (sub < 20) s1body<1,1,0>(pool,xh,xl,wh,wl,zb16,yd,n0,sub-17,mz,nl,tid);
  else               s1body<1,1,1>(pool,xh,xl,wh,wl,zb16,yd,n0,sub-20,mz,nl,tid);
}

// ---- stage 2: gather parity subplanes (padded class-dense y) + separable FIR + bias ----
__global__ __launch_bounds__(256) void stage2d(const float* __restrict__ yd, const float* __restrict__ bias,
                                               float* __restrict__ out, int n0){
  __shared__ float raw[33][36];
  __shared__ float fx[35][36];
  const int tid=threadIdx.x;
  const int zg=blockIdx.x, oc=blockIdx.y, nl=blockIdx.z;
  const float* yb = yd + (size_t)(nl*128+oc)*VOLP;
  const float b = bias[oc];
  float* ob = out + (size_t)((n0+nl)*128+oc)*32768;
  for (int t2=tid; t2<1188; t2+=256) raw[t2/36][t2%36] = 0.f;
  if (tid < 72){ fx[(tid>=36)?34:0][tid%36] = 0.f; }
  __syncthreads();
  float a0[4]={0,0,0,0}, a1[4]={0,0,0,0}, a2[4]={0,0,0,0};
  #pragma unroll 1
  for (int s=0; s<19; ++s){
    int uz = zg*16 - 1 + s;
    if ((u32)uz < 33u){
      const int cz = uz & 1, zi = uz >> 1;
      #pragma unroll
      for (int cy=0; cy<2; ++cy)
        #pragma unroll
        for (int cx=0; cx<2; ++cx){
          const int DXc = 17-cx;
          const int NXYc = (17-cy)*DXc;
          const int NXYPc = cls_nxyp(cy*2+cx);
          const int yoff = (cz ? cls_yoff2(4+cy*2+cx) : cls_yoff2(cy*2+cx)) + zi*NXYPc;
          const float* sp = yb + yoff;
          for (int s2=tid; s2<NXYc; s2+=256){
            int r = s2/DXc, c2 = s2 - r*DXc;
            raw[2*r+cy][2*c2+cx+1] = __builtin_nontemporal_load(sp + s2);
          }
        }
    } else {
      for (int t2=tid; t2<1188; t2+=256) raw[t2/36][t2%36] = 0.f;
    }
    __syncthreads();
    for (int t2=tid; t2<1056; t2+=256){
      int uy = t2>>5, ox = t2&31;
      fx[uy+1][ox] = 0.25f*raw[uy][ox] + 0.75f*raw[uy][ox+1]
                   + 0.75f*raw[uy][ox+2] + 0.25f*raw[uy][ox+3];
    }
    __syncthreads();
    #pragma unroll
    for (int k=0;k<4;++k){
      int pos = tid + k*256;
      int oy = pos>>5, ox = pos&31;
      float fv = 0.25f*fx[oy][ox] + 0.75f*fx[oy+1][ox]
               + 0.75f*fx[oy+2][ox] + 0.25f*fx[oy+3][ox];
      if (s >= 3){
        int oz = zg*16 + s - 3;
        __builtin_nontemporal_store(a0[k] + 0.25f*fv + b, ob + (size_t)oz*1024 + pos);
      }
      a0[k] = a1[k] + 0.75f*fv;
      a1[k] = a2[k] + 0.75f*fv;
      a2[k] = 0.25f*fv;
    }
    __syncthreads();
  }
}

extern "C" void kernel_launch(void* const* d_in, const int* in_sizes, int n_in,
                              void* d_out, int out_size, void* d_ws, size_t ws_size,
                              hipStream_t stream) {
  const float* x    = (const float*)d_in[0];
  const float* w    = (const float*)d_in[1];
  const float* bias = (const float*)d_in[2];
  float* out = (float*)d_out;

  float* zb = (float*)d_ws;
  u16* wh = (u16*)(zb + ZBF);
  u16* wl = wh + WRE;
  u16* xh = wl + WRE;
  u16* xl = xh + XTE;
  float* yd = (float*)(xl + XTE);
  size_t base = (size_t)ZBF*4 + (size_t)(2*WRE + 2*XTE)*2;

  int nChunk = 1;
  if      (ws_size >= base + (size_t)8*128*VOLP*4) nChunk=8;
  else if (ws_size >= base + (size_t)4*128*VOLP*4) nChunk=4;
  else if (ws_size >= base + (size_t)2*128*VOLP*4) nChunk=2;

  prep_w2<<<dim3(WRE/256), 256, 0, stream>>>(w, wh, wl, zb);
  prep_x<<<dim3(XTE/256), 256, 0, stream>>>(x, xh, xl);

  const u16* zb16 = (const u16*)zb;
  if (nChunk == 8){
    stage1f<<<dim3(2904,1,1),256,0,stream>>>(xh,xl,wh,wl,zb16,yd,0);
    stage2d<<<dim3(2,128,8),256,0,stream>>>(yd,bias,out,0);
  } else {
    for (int n0=0; n0<NBATCH; n0+=nChunk){
      stage1f<<<dim3(363,1,nChunk),256,0,stream>>>(xh,xl,wh,wl,zb16,yd,n0);
      stage2d<<<dim3(2,128,nChunk),256,0,stream>>>(yd,bias,out,n0);
    }
  }
}

// Round 14
// 226.894 us; speedup vs baseline: 1.6284x; 1.5555x over previous
//
#include <hip/hip_runtime.h>
#include <string.h>

typedef __attribute__((ext_vector_type(4))) float f32x4;
typedef __attribute__((ext_vector_type(8))) _Float16 f16x8;
typedef unsigned short u16;
typedef unsigned int   u32;

#define NBATCH 8
#define ICN 256
#define OCN 128
#define VOLP 36432     // padded per-(n,oc) y volume (all classes, 16-float aligned)
#define WRE 884736     // 27*8*8*512 = 27*256*128
#define XTE 8388608    // 8*256*4096
#define ZBF 4096       // zero-buffer floats (16 KB)
// staging: 2 plane buffers x 170 pos x 32 ic x 2B = 2*10880 B = 21760
#define S1POOL 33792   // epilogue transpose 4*64*33*4 dominates

// padded class offsets / plane strides (16-float aligned)
__host__ __device__ constexpr int cls_yoff2(int c){
  return (c==0)?0:(c==1)?5168:(c==2)?9792:(c==3)?14416:
         (c==4)?18768:(c==5)?23632:(c==6)?27984:32336;
}
__host__ __device__ constexpr int cls_nxyp(int c){
  return ((c&3)==0)?304:((c&3)==3)?256:272;
}

__device__ __forceinline__ u16 f2h(float v){
  _Float16 h = (_Float16)v;       // v_cvt_f16_f32, RNE
  u16 u; memcpy(&u, &h, 2);
  return u;
}

#define GLOAD16(gp, lp)                                                        \
  __builtin_amdgcn_global_load_lds(                                            \
      (const __attribute__((address_space(1))) void*)(gp),                     \
      (__attribute__((address_space(3))) void*)(lp), 16, 0, 0)

// ---- prep_w: w[oc][ic][27] fp32 -> wh[tap27][icc8][og8][lane64][e8] f16 ----
// also zeroes the 16 KB zero-buffer (blocks 0..15)
__global__ __launch_bounds__(256) void prep_w(const float* __restrict__ w,
                                              u16* __restrict__ wh,
                                              float* __restrict__ zb){
  if (blockIdx.x < 16) zb[blockIdx.x*256 + threadIdx.x] = 0.f;
  int idx = blockIdx.x*256 + threadIdx.x;   // WRE exactly
  int e = idx&7, ln=(idx>>3)&63, og=(idx>>9)&7, icc=(idx>>12)&7, tt=idx>>15;
  int oc = og*16 + (ln&15);
  int ic = icc*32 + ((ln>>4)&3)*8 + e;
  const int toffs[8] = {0,8,12,16,18,22,24,26};
  const int tcnt[8]  = {8,4,4,2,4,2,2,1};
  int c=0, t=0;
  #pragma unroll
  for (int cc=0; cc<8; ++cc)
    if (tt>=toffs[cc] && tt<toffs[cc]+tcnt[cc]){ c=cc; t=tt-toffs[cc]; }
  int ez=c>>2, ey=(c>>1)&1, ex=c&1;
  int ty=2-ey, tx=2-ex;
  int ax=t%tx, ay=(t/tx)%ty, az=t/(tx*ty);
  int qz = ez?1:(az?2:0), qy = ey?1:(ay?2:0), qx = ex?1:(ax?2:0);
  wh[idx] = f2h(w[((size_t)oc*ICN + ic)*27 + (qz*3+qy)*3+qx]);
}

// ---- prep_x: x[n][ic][4096] fp32 -> xh[n][icc8][4096 pos][32 ic] f16 ----
__global__ __launch_bounds__(256) void prep_x(const float* __restrict__ x,
                                              u16* __restrict__ xh){
  u32 o = blockIdx.x*256 + threadIdx.x;   // XTE exactly
  int il = o & 31, p = (o>>5)&4095, icc = (o>>17)&7, n = o>>20;
  xh[o] = f2h(x[(size_t)(n*256 + icc*32 + il)*4096 + p]);
}

// ---- async A-plane staging: 680 chunks of 16 B ----
// wave wv handles chunks [wv*170, (wv+1)*170) -> exactly 3 gload_lds per wave
// chunk s: pos = s>>2 (10 rows x 17 x), icg = s&3; lds byte = s*16
#define S1_ISSUE(BUFBYTE, ICCV, AZV)                                           \
  {                                                                            \
    _Pragma("unroll")                                                          \
    for (int j_=0; j_<3; ++j_){                                                \
      const int r_ = j_*64 + ln;                                               \
      if (r_ < 170){                                                           \
        const int s_ = wv*170 + r_;                                            \
        const int icg_ = s_&3, pos_ = s_>>2;                                   \
        const int xi_ = pos_%17, yi_ = pos_/17;                                \
        const int zc_ = EZ ? mz : (mz-1+(AZV));                                \
        const int yc_ = my0 + yi_ + (EY-1);                                    \
        const int xc_ = xi_ + (EX-1);                                          \
        const bool inb_ = (u32)zc_<16u && (u32)yc_<16u && (u32)xc_<16u;        \
        const size_t g_ = nbase + (size_t)(ICCV)*131072                        \
                        + (size_t)((zc_*256+yc_*16+xc_)*32 + icg_*8);          \
        const u16* gh_ = inb_ ? (xh+g_) : zb16;                                \
        char* lh_ = pool + (BUFBYTE) + s_*16;                                  \
        GLOAD16(gh_, lh_);                                                     \
      }                                                                        \
    }                                                                          \
  }

// ---- stage 1 body: per-class dense conv via f16 MFMA; B-frags from L2 ----
// block 256 (4 waves): wave = (mhalf = wv&1)*64m x (ochalf = wv>>1)*64oc
// A staged via double-buffered global_load_lds, counted-vmcnt pipeline
template<int EZ,int EY,int EX>
__device__ __forceinline__ void s1body(char* pool,
                                       const u16* __restrict__ xh,
                                       const u16* __restrict__ wh,
                                       const u16* __restrict__ zb16,
                                       float* __restrict__ yd, int n0, int mt, int mz, int nl, int tid)
{
  constexpr int TZ=2-EZ, TY=2-EY, TX=2-EX;
  constexpr int DX=17-EX;
  constexpr int DY=17-EY;
  constexpr int NXY=DY*DX;
  constexpr int CLS = EZ*4+EY*2+EX;
  constexpr int YOFF = cls_yoff2(CLS);
  constexpr int NXYP = cls_nxyp(CLS);
  constexpr int W27 = (CLS==0)?0:(CLS==1)?8:(CLS==2)?12:(CLS==3)?16:
                      (CLS==4)?18:(CLS==5)?22:(CLS==6)?24:26;
  constexpr int NST = TZ*8;        // total plane-stages
  u16* AsU = (u16*)pool;           // per buffer: 5440 u16 (10880 B)

  const int wv=tid>>6, ln=tid&63;
  const int mhalf = wv&1, ochalf = wv>>1;
  const int my0=(mt*128)/DX;

  int posA[4];
  #pragma unroll
  for (int fi=0; fi<4; ++fi){
    int m = mt*128 + mhalf*64 + fi*16 + (ln&15);
    if (m > NXY-1) m = NXY-1;      // clamp (stores guarded)
    int my=m/DX, mx=m-my*DX;
    posA[fi] = ((my-my0)*17 + mx)*32 + (ln>>4)*8;
  }

  f32x4 acc[4][4];
  #pragma unroll
  for (int i=0;i<4;++i)
    #pragma unroll
    for (int j=0;j<4;++j) acc[i][j]=(f32x4){0.f,0.f,0.f,0.f};

  const size_t nbase = (size_t)(n0+nl)*(ICN*4096);

  S1_ISSUE(0, 0, 0);

  int st = 0;
  #pragma unroll 1
  for (int icc=0; icc<8; ++icc){
    #pragma unroll
    for (int az=0; az<TZ; ++az){
      const int cur = st & 1;
      const bool have_next = (st+1) < NST;
      if (have_next){
        const int nicc = (az+1<TZ)?icc:(icc+1);
        const int naz  = (az+1<TZ)?(az+1):0;
        S1_ISSUE((cur^1)*10880, nicc, naz);
        // wait only for the PREVIOUS stage's 3 DMAs (in-order vmcnt)
        asm volatile("s_waitcnt vmcnt(3)" ::: "memory");
      } else {
        asm volatile("s_waitcnt vmcnt(0)" ::: "memory");
      }
      asm volatile("s_barrier" ::: "memory");   // current buffer fully written
      const int curo = cur*5440;

      #pragma unroll
      for (int ay=0; ay<TY; ++ay)
      #pragma unroll
      for (int ax=0; ax<TX; ++ax){
        const int t = (az*TY+ay)*TX+ax;
        const int toff = (ay*17+ax)*32;
        f16x8 ah[4];
        #pragma unroll
        for (int fi=0; fi<4; ++fi)
          ah[fi] = *(const f16x8*)&AsU[curo + posA[fi]+toff];
        const u16* bp = wh + (size_t)(((W27+t)*8+icc)*8)*512 + (ochalf*4)*512 + ln*8;
        f16x8 bh[4];
        #pragma unroll
        for (int og=0; og<4; ++og) bh[og] = *(const f16x8*)(bp + og*512);
        #pragma unroll
        for (int fi=0; fi<4; ++fi)
          #pragma unroll
          for (int og=0; og<4; ++og)
            acc[fi][og] = __builtin_amdgcn_mfma_f32_16x16x32_f16(ah[fi], bh[og], acc[fi][og],0,0,0);
      }
      // raw barrier (no vmcnt drain): all waves done READING cur before next
      // stage's DMA overwrites it.
      asm volatile("s_barrier" ::: "memory");
      ++st;
    }
  }

  // epilogue: per-wave transpose (2 half-passes of 32 m), aligned dense nt store
  float* tr = (float*)pool + wv*(64*33);
  #pragma unroll
  for (int pass=0; pass<2; ++pass){
    #pragma unroll
    for (int fi=0; fi<2; ++fi)
      #pragma unroll
      for (int og=0; og<4; ++og)
        #pragma unroll
        for (int j=0; j<4; ++j)
          tr[(og*16+(ln&15))*33 + fi*16 + (ln>>4)*4 + j] = acc[pass*2+fi][og][j];
    int m = mt*128 + mhalf*64 + pass*32 + (ln&31);
    bool valid = m < NXY;
    size_t lbase = (size_t)YOFF + (size_t)mz*NXYP + (valid ? m : 0);
    #pragma unroll 4
    for (int i=0; i<32; ++i){
      int r = 2*i + (ln>>5);
      float v = tr[r*33 + (ln&31)];
      int oc = ochalf*64 + r;
      if (valid)
        __builtin_nontemporal_store(v, yd + (size_t)(nl*128 + oc)*VOLP + lbase);
    }
  }
}

// ---- fused stage 1 ----
__global__ __launch_bounds__(256,3) void stage1f(const u16* __restrict__ xh,
                                                 const u16* __restrict__ wh,
                                                 const u16* __restrict__ zb16,
                                                 float* __restrict__ yd, int n0){
  __shared__ __align__(16) char pool[S1POOL];
  int bid = blockIdx.x, nl, tid = threadIdx.x;
  if (gridDim.z == 1){ nl = bid & 7; bid >>= 3; }
  else               { nl = blockIdx.z; }
  int mz, sub;
  if (bid < 352){ mz = bid/22; sub = bid - mz*22; }
  else          { mz = 16;     sub = bid - 352;   }
  if      (sub <  3) s1body<0,0,0>(pool,xh,wh,zb16,yd,n0,sub   ,mz,nl,tid);
  else if (sub <  6) s1body<0,0,1>(pool,xh,wh,zb16,yd,n0,sub- 3,mz,nl,tid);
  else if (sub <  9) s1body<0,1,0>(pool,xh,wh,zb16,yd,n0,sub- 6,mz,nl,tid);
  else if (sub < 11) s1body<0,1,1>(pool,xh,wh,zb16,yd,n0,sub- 9,mz,nl,tid);
  else if (sub < 14) s1body<1,0,0>(pool,xh,wh,zb16,yd,n0,sub-11,mz,nl,tid);
  else if (sub < 17) s1body<1,0,1>(pool,xh,wh,zb16,yd,n0,sub-14,mz,nl,tid);
  else if (sub < 20) s1body<1,1,0>(pool,xh,wh,zb16,yd,n0,sub-17,mz,nl,tid);
  else               s1body<1,1,1>(pool,xh,wh,zb16,yd,n0,sub-20,mz,nl,tid);
}

// ---- stage 2: gather parity subplanes (padded class-dense y) + separable FIR + bias ----
__global__ __launch_bounds__(256) void stage2d(const float* __restrict__ yd, const float* __restrict__ bias,
                                               float* __restrict__ out, int n0){
  __shared__ float raw[33][36];
  __shared__ float fx[35][36];
  const int tid=threadIdx.x;
  const int zg=blockIdx.x, oc=blockIdx.y, nl=blockIdx.z;
  const float* yb = yd + (size_t)(nl*128+oc)*VOLP;
  const float b = bias[oc];
  float* ob = out + (size_t)((n0+nl)*128+oc)*32768;
  for (int t2=tid; t2<1188; t2+=256) raw[t2/36][t2%36] = 0.f;
  if (tid < 72){ fx[(tid>=36)?34:0][tid%36] = 0.f; }
  __syncthreads();
  float a0[4]={0,0,0,0}, a1[4]={0,0,0,0}, a2[4]={0,0,0,0};
  #pragma unroll 1
  for (int s=0; s<19; ++s){
    int uz = zg*16 - 1 + s;
    if ((u32)uz < 33u){
      const int cz = uz & 1, zi = uz >> 1;
      #pragma unroll
      for (int cy=0; cy<2; ++cy)
        #pragma unroll
        for (int cx=0; cx<2; ++cx){
          const int DXc = 17-cx;
          const int NXYc = (17-cy)*DXc;
          const int NXYPc = cls_nxyp(cy*2+cx);
          const int yoff = (cz ? cls_yoff2(4+cy*2+cx) : cls_yoff2(cy*2+cx)) + zi*NXYPc;
          const float* sp = yb + yoff;
          for (int s2=tid; s2<NXYc; s2+=256){
            int r = s2/DXc, c2 = s2 - r*DXc;
            raw[2*r+cy][2*c2+cx+1] = __builtin_nontemporal_load(sp + s2);
          }
        }
    } else {
      for (int t2=tid; t2<1188; t2+=256) raw[t2/36][t2%36] = 0.f;
    }
    __syncthreads();
    for (int t2=tid; t2<1056; t2+=256){
      int uy = t2>>5, ox = t2&31;
      fx[uy+1][ox] = 0.25f*raw[uy][ox] + 0.75f*raw[uy][ox+1]
                   + 0.75f*raw[uy][ox+2] + 0.25f*raw[uy][ox+3];
    }
    __syncthreads();
    #pragma unroll
    for (int k=0;k<4;++k){
      int pos = tid + k*256;
      int oy = pos>>5, ox = pos&31;
      float fv = 0.25f*fx[oy][ox] + 0.75f*fx[oy+1][ox]
               + 0.75f*fx[oy+2][ox] + 0.25f*fx[oy+3][ox];
      if (s >= 3){
        int oz = zg*16 + s - 3;
        __builtin_nontemporal_store(a0[k] + 0.25f*fv + b, ob + (size_t)oz*1024 + pos);
      }
      a0[k] = a1[k] + 0.75f*fv;
      a1[k] = a2[k] + 0.75f*fv;
      a2[k] = 0.25f*fv;
    }
    __syncthreads();
  }
}

extern "C" void kernel_launch(void* const* d_in, const int* in_sizes, int n_in,
                              void* d_out, int out_size, void* d_ws, size_t ws_size,
                              hipStream_t stream) {
  const float* x    = (const float*)d_in[0];
  const float* w    = (const float*)d_in[1];
  const float* bias = (const float*)d_in[2];
  float* out = (float*)d_out;

  float* zb = (float*)d_ws;
  u16* wh = (u16*)(zb + ZBF);
  u16* xh = wh + WRE;
  float* yd = (float*)(xh + XTE);
  size_t base = (size_t)ZBF*4 + (size_t)(WRE + XTE)*2;

  int nChunk = 1;
  if      (ws_size >= base + (size_t)8*128*VOLP*4) nChunk=8;
  else if (ws_size >= base + (size_t)4*128*VOLP*4) nChunk=4;
  else if (ws_size >= base + (size_t)2*128*VOLP*4) nChunk=2;

  prep_w<<<dim3(WRE/256), 256, 0, stream>>>(w, wh, zb);
  prep_x<<<dim3(XTE/256), 256, 0, stream>>>(x, xh);

  const u16* zb16 = (const u16*)zb;
  if (nChunk == 8){
    stage1f<<<dim3(2904,1,1),256,0,stream>>>(xh,wh,zb16,yd,0);
    stage2d<<<dim3(2,128,8),256,0,stream>>>(yd,bias,out,0);
  } else {
    for (int n0=0; n0<NBATCH; n0+=nChunk){
      stage1f<<<dim3(363,1,nChunk),256,0,stream>>>(xh,wh,zb16,yd,n0);
      stage2d<<<dim3(2,128,nChunk),256,0,stream>>>(yd,bias,out,n0);
    }
  }
}